// Round 4
// baseline (790.108 us; speedup 1.0000x reference)
//
#include <hip/hip_runtime.h>
#include <hip/hip_cooperative_groups.h>
#include <math.h>

namespace cg = cooperative_groups;

#define ROWS   8192
#define LQ     4096
#define NHEAD  8
#define NLVL   4
#define NPTS   4
#define HDIM   32

typedef __attribute__((ext_vector_type(8))) short v8s;
typedef __attribute__((ext_vector_type(4))) float v4f;
typedef __attribute__((ext_vector_type(8))) unsigned short v8u;

__device__ __forceinline__ unsigned short f2bf(float x) {
    unsigned int u = __float_as_uint(x);
    u += 0x7fffu + ((u >> 16) & 1u);
    return (unsigned short)(u >> 16);
}
__device__ __forceinline__ float bf2f(unsigned short x) {
    return __uint_as_float(((unsigned int)x) << 16);
}

// async global -> LDS, 16B per lane; LDS dest = wave-uniform base + lane*16
__device__ __forceinline__ void glds16(const void* g, void* l) {
    __builtin_amdgcn_global_load_lds(
        (const __attribute__((address_space(1))) unsigned int*)g,
        (__attribute__((address_space(3))) unsigned int*)l, 16, 0, 0);
}

// ---------------------------------------------------------------------------
// Phase helpers (shared between the cooperative mega-kernel and the
// discrete-kernel fallback).
// ---------------------------------------------------------------------------

// weight transpose tile: 32x32, fp32 in -> bf16 [N][K] out
__device__ __forceinline__ void trans_tile(float (*t)[33],
                                           const float* __restrict__ in,
                                           unsigned short* __restrict__ out,
                                           int K, int N, int ldout, int n_off,
                                           int bx, int by, int tid)
{
    int tx = tid & 31, ty = tid >> 5;           // 32 x 8
    int k0 = by << 5, n0 = bx << 5;
    #pragma unroll
    for (int i = 0; i < 4; i++)
        t[ty + i * 8][tx] = in[(size_t)(k0 + ty + i * 8) * N + n0 + tx];
    __syncthreads();
    #pragma unroll
    for (int i = 0; i < 4; i++)
        out[(size_t)(n_off + n0 + ty + i * 8) * ldout + k0 + tx] = f2bf(t[tx][ty + i * 8]);
}

// one prep work unit (0..1760)
__device__ __forceinline__ void prep_unit(int u, int tid, float (*tt)[33],
    const float* vw, const float* ofw, const float* aww, const float* pw,
    const float* w1, const float* w2,
    unsigned short* Btcat, unsigned short* pwT, unsigned short* w1T,
    unsigned short* w2T,
    const float* vb, const float* ofb, const float* awb, float* biascat,
    const float* src, unsigned short* srcbf)
{
    if (u < 64) {
        trans_tile(tt, vw, Btcat, 256, 256, 256, 0, u & 7, u >> 3, tid);
    } else if (u < 128) {
        int t = u - 64; trans_tile(tt, ofw, Btcat, 256, 256, 256, 256, t & 7, t >> 3, tid);
    } else if (u < 160) {
        int t = u - 128; trans_tile(tt, aww, Btcat, 256, 128, 256, 512, t & 3, t >> 2, tid);
    } else if (u < 224) {
        int t = u - 160; trans_tile(tt, pw, pwT, 256, 256, 256, 0, t & 7, t >> 3, tid);
    } else if (u < 480) {
        int t = u - 224; trans_tile(tt, w1, w1T, 256, 1024, 256, 0, t & 31, t >> 5, tid);
    } else if (u < 736) {
        int t = u - 480; trans_tile(tt, w2, w2T, 1024, 256, 1024, 0, t & 7, t >> 3, tid);
    } else if (u == 736) {
        biascat[tid] = vb[tid];
        biascat[tid + 256] = ofb[tid];
        if (tid < 128) biascat[tid + 512] = awb[tid];
    } else {
        int n = u - 737;                         // 1024 copy units
        size_t base = (size_t)n * 2048 + (size_t)tid * 8;
        float4 a = *(const float4*)(src + base);
        float4 b = *(const float4*)(src + base + 4);
        v8u o;
        o[0] = f2bf(a.x); o[1] = f2bf(a.y); o[2] = f2bf(a.z); o[3] = f2bf(a.w);
        o[4] = f2bf(b.x); o[5] = f2bf(b.y); o[6] = f2bf(b.z); o[7] = f2bf(b.w);
        *(v8u*)(srcbf + base) = o;
    }
}

// BM=64/BN=128/BK=32 GEMM tile, 2-buffer staging (verified R1 structure).
// SMEM layout: As[2][2048] us @0, Bs[2][4096] us @4096 (12288 us total).
template<bool PROJ, bool OUTBF, bool RELU>
__device__ __forceinline__ void gemm128_phase(
    unsigned short* SMEM, int gx, int gy,
    const unsigned short* __restrict__ A,   // bf16 [M][K]
    const unsigned short* __restrict__ Bt,  // bf16 [N][K]
    const float* __restrict__ bias,
    void* __restrict__ Cout,
    unsigned short* __restrict__ vbf,       // PROJ only
    const float* __restrict__ refp,         // PROJ only
    float* __restrict__ oloc,               // PROJ only
    int N, int K)
{
    unsigned short (*As)[2048] = (unsigned short (*)[2048])SMEM;
    unsigned short (*Bs)[4096] = (unsigned short (*)[4096])(SMEM + 4096);
    const int tid = threadIdx.x;
    const int row0 = gy << 6, col0 = gx << 7;
    const int wid = tid >> 6, lane = tid & 63;
    const int wm = wid & 1, wn = wid >> 1;
    const int lr = lane & 15, kq = lane >> 4;

    auto stage = [&](int k0, int b) {
        {
            int c = tid;
            int row = c >> 2;
            int kk = ((c & 3) + (row >> 2)) & 3;
            glds16(A + (size_t)(row0 + row) * K + k0 + kk * 8, &As[b][(wid * 64) * 8]);
        }
        #pragma unroll
        for (int i = 0; i < 2; i++) {
            int c = wid * 128 + i * 64 + lane;
            int row = c >> 2;
            int kk = ((c & 3) + (row >> 2)) & 3;
            glds16(Bt + (size_t)(col0 + row) * K + k0 + kk * 8,
                   &Bs[b][(wid * 128 + i * 64) * 8]);
        }
    };

    v4f acc[2][4];
    #pragma unroll
    for (int i = 0; i < 2; i++)
        #pragma unroll
        for (int j = 0; j < 4; j++) acc[i][j] = (v4f){0.f, 0.f, 0.f, 0.f};

    stage(0, 0);
    int cur = 0;
    for (int k0 = 0; k0 < K; k0 += 32) {
        __syncthreads();
        if (k0 + 32 < K) stage(k0 + 32, cur ^ 1);
        v8s bf[4];
        #pragma unroll
        for (int nt = 0; nt < 4; nt++) {
            int row = wn * 64 + nt * 16 + lr;
            int s = (kq - (row >> 2)) & 3;
            bf[nt] = *(const v8s*)(&Bs[cur][(row * 4 + s) * 8]);
        }
        #pragma unroll
        for (int mt = 0; mt < 2; mt++) {
            int row = wm * 32 + mt * 16 + lr;
            int s = (kq - (row >> 2)) & 3;
            v8s af = *(const v8s*)(&As[cur][(row * 4 + s) * 8]);
            #pragma unroll
            for (int nt = 0; nt < 4; nt++)
                acc[mt][nt] = __builtin_amdgcn_mfma_f32_16x16x32_bf16(af, bf[nt], acc[mt][nt], 0, 0, 0);
        }
        cur ^= 1;
    }
    __syncthreads();                            // SMEM safe for next tile

    const int rq = lane >> 4;
    #pragma unroll
    for (int mt = 0; mt < 2; mt++) {
        #pragma unroll
        for (int nt = 0; nt < 4; nt++) {
            int col = col0 + wn * 64 + nt * 16 + lr;
            float bv = bias[col];
            #pragma unroll
            for (int i = 0; i < 4; i++) {
                int row = row0 + wm * 32 + mt * 16 + rq * 4 + i;
                float v = acc[mt][nt][i] + bv;
                if (RELU) v = fmaxf(v, 0.f);
                if (PROJ) {
                    if (col < 256) {
                        int b = row >> 12, rb = row & 4095;
                        int l = rb >> 10, pix = rb & 1023;
                        int h = col >> 5, d = col & 31;
                        size_t idx = ((size_t)(((b << 2) + l) * 8 + h) << 15) + (pix << 5) + d;
                        vbf[idx] = f2bf(v);
                    } else if (col < 512) {
                        int colm = col - 256;
                        int l = (colm >> 3) & 3, cc = colm & 1;
                        oloc[(size_t)row * 256 + colm] =
                            refp[(size_t)row * 8 + l * 2 + cc] + v * (1.f / 32.f);
                    } else {
                        ((float*)Cout)[(size_t)row * 128 + col - 512] = v;
                    }
                } else if (OUTBF) {
                    ((unsigned short*)Cout)[(size_t)row * N + col] = f2bf(v);
                } else {
                    ((float*)Cout)[(size_t)row * N + col] = v;
                }
            }
        }
    }
}

// BM=16, full-N=256 GEMM + residual + LayerNorm tile. 2-buffer staging.
// SMEM: As[2][512] us @0, Bs[2][8192] us @1024 (17408 us total).
template<bool RESF32, bool OUTF32>
__device__ __forceinline__ void gemmln_phase(
    unsigned short* SMEM, float (*red)[16][4], int u,
    const unsigned short* __restrict__ A,   // bf16 [M][K]
    const unsigned short* __restrict__ Bt,  // bf16 [256][K]
    const float* __restrict__ bias,
    const void* __restrict__ resv,          // [M][256] fp32 or bf16
    const float* __restrict__ g,
    const float* __restrict__ b,
    void* __restrict__ outv,                // [M][256] fp32 or bf16
    int K)
{
    unsigned short (*As)[512]  = (unsigned short (*)[512])SMEM;
    unsigned short (*Bs)[8192] = (unsigned short (*)[8192])(SMEM + 1024);
    const int tid = threadIdx.x;
    const int row0 = u << 4;
    const int wid = tid >> 6, lane = tid & 63;
    const int lr = lane & 15, kq = lane >> 4;
    const int rq = kq;

    auto stage = [&](int k0, int bb) {
        if (wid == 0) {                         // A: 64 chunks, wave 0
            int c = lane;
            int row = c >> 2;
            int kk = ((c & 3) + (row >> 2)) & 3;
            glds16(A + (size_t)(row0 + row) * K + k0 + kk * 8, &As[bb][0]);
        }
        #pragma unroll
        for (int i = 0; i < 4; i++) {           // B: 1024 chunks, 4/thread
            int c = i * 256 + tid;
            int brow = c >> 2;
            int kk = ((c & 3) + (brow >> 2)) & 3;
            glds16(Bt + (size_t)brow * K + k0 + kk * 8,
                   &Bs[bb][(i * 256 + wid * 64) * 8]);
        }
    };

    v4f acc[4];
    #pragma unroll
    for (int i = 0; i < 4; i++) acc[i] = (v4f){0.f, 0.f, 0.f, 0.f};

    stage(0, 0);
    int cur = 0;
    for (int k0 = 0; k0 < K; k0 += 32) {
        __syncthreads();
        if (k0 + 32 < K) stage(k0 + 32, cur ^ 1);
        v8s bf[4];
        #pragma unroll
        for (int ct = 0; ct < 4; ct++) {
            int col = wid * 64 + ct * 16 + lr;
            int s = (kq - (col >> 2)) & 3;
            bf[ct] = *(const v8s*)(&Bs[cur][(col * 4 + s) * 8]);
        }
        {
            int row = lr;
            int s = (kq - (row >> 2)) & 3;
            v8s af = *(const v8s*)(&As[cur][(row * 4 + s) * 8]);
            #pragma unroll
            for (int ct = 0; ct < 4; ct++)
                acc[ct] = __builtin_amdgcn_mfma_f32_16x16x32_bf16(af, bf[ct], acc[ct], 0, 0, 0);
        }
        cur ^= 1;
    }

    float tv[4][4];
    float s1[4], s2[4];
    #pragma unroll
    for (int i = 0; i < 4; i++) { s1[i] = 0.f; s2[i] = 0.f; }
    #pragma unroll
    for (int ct = 0; ct < 4; ct++) {
        int col = wid * 64 + ct * 16 + lr;
        float bv = bias[col];
        #pragma unroll
        for (int i = 0; i < 4; i++) {
            int row = row0 + rq * 4 + i;
            float rv;
            if (RESF32) rv = ((const float*)resv)[(size_t)row * 256 + col];
            else        rv = bf2f(((const unsigned short*)resv)[(size_t)row * 256 + col]);
            float v = acc[ct][i] + bv + rv;
            tv[ct][i] = v;
            s1[i] += v;
            s2[i] += v * v;
        }
    }
    #pragma unroll
    for (int o = 1; o < 16; o <<= 1) {
        #pragma unroll
        for (int i = 0; i < 4; i++) {
            s1[i] += __shfl_xor(s1[i], o);
            s2[i] += __shfl_xor(s2[i], o);
        }
    }
    if (lr == 0) {
        #pragma unroll
        for (int i = 0; i < 4; i++) {
            red[0][rq * 4 + i][wid] = s1[i];
            red[1][rq * 4 + i][wid] = s2[i];
        }
    }
    __syncthreads();
    float mu[4], rstd[4];
    #pragma unroll
    for (int i = 0; i < 4; i++) {
        int rl = rq * 4 + i;
        float S1 = red[0][rl][0] + red[0][rl][1] + red[0][rl][2] + red[0][rl][3];
        float S2 = red[1][rl][0] + red[1][rl][1] + red[1][rl][2] + red[1][rl][3];
        float m = S1 * (1.f / 256.f);
        mu[i] = m;
        rstd[i] = rsqrtf(S2 * (1.f / 256.f) - m * m + 1e-5f);
    }
    #pragma unroll
    for (int ct = 0; ct < 4; ct++) {
        int col = wid * 64 + ct * 16 + lr;
        float gg = g[col], bb = b[col];
        #pragma unroll
        for (int i = 0; i < 4; i++) {
            int row = row0 + rq * 4 + i;
            float o = (tv[ct][i] - mu[i]) * rstd[i] * gg + bb;
            if (OUTF32) ((float*)outv)[(size_t)row * 256 + col] = o;
            else        ((unsigned short*)outv)[(size_t)row * 256 + col] = f2bf(o);
        }
    }
    __syncthreads();                            // SMEM/red safe for next tile
}

// fused softmax + deformable gather, one work unit (0..4095)
__device__ __forceinline__ void gather_phase(int u,
    const float* __restrict__ po,
    const unsigned short* __restrict__ vbf,
    const float* __restrict__ loc,
    unsigned short* __restrict__ attn_bf)
{
    int tid = threadIdx.x;
    int g = tid >> 4, l = (tid >> 2) & 3, d8 = tid & 3;
    int h = u & 7;
    int r = (u >> 3) * 16 + g;
    int b = r >> 12;

    float locv[8];
    *(float4*)(locv)     = *(const float4*)(loc + (size_t)r * 256 + h * 32 + l * 8);
    *(float4*)(locv + 4) = *(const float4*)(loc + (size_t)r * 256 + h * 32 + l * 8 + 4);

    float w4[4];
    *(float4*)(w4) = *(const float4*)(po + (size_t)r * 128 + h * 16 + l * 4);
    float m = fmaxf(fmaxf(w4[0], w4[1]), fmaxf(w4[2], w4[3]));
    m = fmaxf(m, __shfl_xor(m, 4));
    m = fmaxf(m, __shfl_xor(m, 8));
    float s = 0.f;
    #pragma unroll
    for (int p = 0; p < 4; p++) { w4[p] = __expf(w4[p] - m); s += w4[p]; }
    s += __shfl_xor(s, 4);
    s += __shfl_xor(s, 8);
    float inv = 1.f / s;

    const unsigned short* vbase =
        vbf + (((size_t)(((b << 2) + l) * 8 + h)) << 15) + d8 * 8;

    float acc[8];
    #pragma unroll
    for (int k = 0; k < 8; k++) acc[k] = 0.f;

    #pragma unroll
    for (int pp = 0; pp < 2; pp++) {
        v8u uv[8];
        float cw[8];
        #pragma unroll
        for (int p2 = 0; p2 < 2; p2++) {
            int p = pp * 2 + p2;
            float xf = locv[p * 2] * 32.f - 0.5f, yf = locv[p * 2 + 1] * 32.f - 0.5f;
            float x0f = floorf(xf), y0f = floorf(yf);
            float fx = xf - x0f, fy = yf - y0f;
            int x0 = (int)x0f, y0 = (int)y0f;
            float wgt = w4[p] * inv;
            #pragma unroll
            for (int dy = 0; dy < 2; dy++) {
                #pragma unroll
                for (int dx = 0; dx < 2; dx++) {
                    int idx = p2 * 4 + dy * 2 + dx;
                    int xi = x0 + dx, yi = y0 + dy;
                    float wt = (dx ? fx : 1.f - fx) * (dy ? fy : 1.f - fy);
                    bool valid = (xi >= 0) & (xi < 32) & (yi >= 0) & (yi < 32);
                    int xc = min(max(xi, 0), 31), yc = min(max(yi, 0), 31);
                    cw[idx] = valid ? (wgt * wt) : 0.f;
                    uv[idx] = *(const v8u*)(vbase + (size_t)((yc << 5) + xc) * 32);
                }
            }
        }
        #pragma unroll
        for (int idx = 0; idx < 8; idx++) {
            float c = cw[idx];
            #pragma unroll
            for (int k = 0; k < 8; k++)
                acc[k] += c * bf2f(uv[idx][k]);
        }
    }
    #pragma unroll
    for (int k = 0; k < 8; k++) {
        acc[k] += __shfl_xor(acc[k], 4);
        acc[k] += __shfl_xor(acc[k], 8);
    }
    if (l == 0) {
        v8u o;
        #pragma unroll
        for (int k = 0; k < 8; k++) o[k] = f2bf(acc[k]);
        *(v8u*)(attn_bf + (size_t)r * 256 + h * 32 + d8 * 8) = o;
    }
}

// ---------------------------------------------------------------------------
// Cooperative mega-kernel: all 6 phases, grid.sync() between them.
// grid = 512 blocks x 256 threads (2 blocks/CU guaranteed co-resident:
// LDS 39.5 KB/block, VGPR capped by launch_bounds(256,2)).
// ---------------------------------------------------------------------------
__global__ __launch_bounds__(256, 2) void mega_k(
    const float* src, const float* refp,
    const float* vw, const float* vb, const float* ofw, const float* ofb,
    const float* aww, const float* awb, const float* pw, const float* pb,
    const float* g1, const float* b1, const float* w1, const float* bi1,
    const float* w2, const float* bi2, const float* g2, const float* b2,
    float* ws, float* out)
{
    __shared__ __align__(16) unsigned short SM[17408];   // 34 KB staging
    __shared__ float red[2][16][4];
    __shared__ float tt[32][33];

    float*          po        = ws;
    unsigned short* value_bf  = (unsigned short*)(ws + 1048576);
    unsigned short* x1_bf     = (unsigned short*)(ws + 2097152);
    unsigned short* attn_bf   = (unsigned short*)(ws + 3145728);
    unsigned short* hidden_bf = (unsigned short*)(ws + 4194304);
    unsigned short* Btcat     = (unsigned short*)(ws + 8388608);
    unsigned short* pwT       = (unsigned short*)(ws + 8470528);
    unsigned short* w1T       = (unsigned short*)(ws + 8503296);
    unsigned short* w2T       = (unsigned short*)(ws + 8634368);
    float*          biascat   = ws + 8765440;
    unsigned short* src_bf    = (unsigned short*)(ws + 8766080);
    float* out_x   = out;
    float* out_loc = out + 2097152;

    cg::grid_group grid = cg::this_grid();
    const int tid = threadIdx.x;
    const int nb  = gridDim.x;

    // phase 0: weight prep + src->bf16
    for (int u = blockIdx.x; u < 1761; u += nb) {
        prep_unit(u, tid, tt, vw, ofw, aww, pw, w1, w2,
                  Btcat, pwT, w1T, w2T, vb, ofb, awb, biascat, src, src_bf);
        __syncthreads();
    }
    __threadfence();
    grid.sync();

    // phase 1: fused projections (N=640)
    for (int u = blockIdx.x; u < 640; u += nb)
        gemm128_phase<true, false, false>(SM, u % 5, u / 5, src_bf, Btcat, biascat,
                                          po, value_bf, refp, out_loc, 640, 256);
    __threadfence();
    grid.sync();

    // phase 2: softmax + deformable gather
    for (int u = blockIdx.x; u < 4096; u += nb)
        gather_phase(u, po, value_bf, out_loc, attn_bf);
    __threadfence();
    grid.sync();

    // phase 3: output projection + residual(src) + LN1 -> x1_bf
    for (int u = blockIdx.x; u < 512; u += nb)
        gemmln_phase<true, false>(SM, red, u, attn_bf, pwT, pb, src, g1, b1,
                                  x1_bf, 256);
    __threadfence();
    grid.sync();

    // phase 4: FFN1 relu -> hidden_bf (N=1024)
    for (int u = blockIdx.x; u < 1024; u += nb)
        gemm128_phase<false, true, true>(SM, u & 7, u >> 3, x1_bf, w1T, bi1,
                                         hidden_bf, nullptr, nullptr, nullptr, 1024, 256);
    __threadfence();
    grid.sync();

    // phase 5: FFN2 + residual(x1_bf) + LN2 -> out_x
    for (int u = blockIdx.x; u < 512; u += nb)
        gemmln_phase<false, true>(SM, red, u, hidden_bf, w2T, bi2, x1_bf, g2, b2,
                                  out_x, 1024);
}

// ---------------------------------------------------------------------------
// Discrete-kernel fallback (same phase bodies) in case cooperative launch
// is rejected by the runtime/capture.
// ---------------------------------------------------------------------------
__global__ __launch_bounds__(256) void prep_w(
    const float* vw, const float* ofw, const float* aww, const float* pw,
    const float* w1, const float* w2,
    unsigned short* Btcat, unsigned short* pwT, unsigned short* w1T,
    unsigned short* w2T,
    const float* vb, const float* ofb, const float* awb, float* biascat,
    const float* src, unsigned short* srcbf)
{
    __shared__ float tt[32][33];
    prep_unit(blockIdx.x, threadIdx.x, tt, vw, ofw, aww, pw, w1, w2,
              Btcat, pwT, w1T, w2T, vb, ofb, awb, biascat, src, srcbf);
}

template<bool PROJ, bool OUTBF, bool RELU>
__global__ __launch_bounds__(256) void gemm128_w(
    const unsigned short* A, const unsigned short* Bt, const float* bias,
    void* Cout, unsigned short* vbf, const float* refp, float* oloc,
    int GX, int N, int K)
{
    __shared__ __align__(16) unsigned short SM[12288];
    int u = blockIdx.x;
    gemm128_phase<PROJ, OUTBF, RELU>(SM, u % GX, u / GX, A, Bt, bias,
                                     Cout, vbf, refp, oloc, N, K);
}

template<bool RESF32, bool OUTF32>
__global__ __launch_bounds__(256) void gemmln_w(
    const unsigned short* A, const unsigned short* Bt, const float* bias,
    const void* resv, const float* g, const float* b, void* outv, int K)
{
    __shared__ __align__(16) unsigned short SM[17408];
    __shared__ float red[2][16][4];
    gemmln_phase<RESF32, OUTF32>(SM, red, blockIdx.x, A, Bt, bias, resv, g, b,
                                 outv, K);
}

__global__ __launch_bounds__(256) void gather_w(
    const float* po, const unsigned short* vbf, const float* loc,
    unsigned short* attn_bf)
{
    gather_phase(blockIdx.x, po, vbf, loc, attn_bf);
}

// ---------------------------------------------------------------------------
extern "C" void kernel_launch(void* const* d_in, const int* in_sizes, int n_in,
                              void* d_out, int out_size, void* d_ws, size_t ws_size,
                              hipStream_t stream)
{
    const float* src   = (const float*)d_in[0];
    const float* refp  = (const float*)d_in[2];
    const float* vw    = (const float*)d_in[3];
    const float* vb    = (const float*)d_in[4];
    const float* ofw   = (const float*)d_in[5];
    const float* ofb   = (const float*)d_in[6];
    const float* aww   = (const float*)d_in[7];
    const float* awb   = (const float*)d_in[8];
    const float* pw    = (const float*)d_in[9];
    const float* pb    = (const float*)d_in[10];
    const float* g1    = (const float*)d_in[11];
    const float* b1    = (const float*)d_in[12];
    const float* w1    = (const float*)d_in[13];
    const float* bi1   = (const float*)d_in[14];
    const float* w2    = (const float*)d_in[15];
    const float* bi2   = (const float*)d_in[16];
    const float* g2    = (const float*)d_in[17];
    const float* b2    = (const float*)d_in[18];

    float* wsf = (float*)d_ws;
    float* outf = (float*)d_out;

    void* args[20] = {
        (void*)&src, (void*)&refp, (void*)&vw, (void*)&vb, (void*)&ofw,
        (void*)&ofb, (void*)&aww, (void*)&awb, (void*)&pw, (void*)&pb,
        (void*)&g1, (void*)&b1, (void*)&w1, (void*)&bi1, (void*)&w2,
        (void*)&bi2, (void*)&g2, (void*)&b2, (void*)&wsf, (void*)&outf
    };
    hipError_t e = hipLaunchCooperativeKernel((void*)mega_k, dim3(512), dim3(256),
                                              args, 0, stream);
    if (e == hipSuccess) return;

    // fallback: discrete kernels
    float*          po        = wsf;
    unsigned short* value_bf  = (unsigned short*)(wsf + 1048576);
    unsigned short* x1_bf     = (unsigned short*)(wsf + 2097152);
    unsigned short* attn_bf   = (unsigned short*)(wsf + 3145728);
    unsigned short* hidden_bf = (unsigned short*)(wsf + 4194304);
    unsigned short* Btcat     = (unsigned short*)(wsf + 8388608);
    unsigned short* pwT       = (unsigned short*)(wsf + 8470528);
    unsigned short* w1T       = (unsigned short*)(wsf + 8503296);
    unsigned short* w2T       = (unsigned short*)(wsf + 8634368);
    float*          biascat   = wsf + 8765440;
    unsigned short* src_bf    = (unsigned short*)(wsf + 8766080);
    float* out_x   = outf;
    float* out_loc = outf + 2097152;

    dim3 blk(256);
    prep_w<<<1761, blk, 0, stream>>>(vw, ofw, aww, pw, w1, w2,
                                     Btcat, pwT, w1T, w2T, vb, ofb, awb, biascat,
                                     src, src_bf);
    gemm128_w<true, false, false><<<640, blk, 0, stream>>>(
        src_bf, Btcat, biascat, po, value_bf, refp, out_loc, 5, 640, 256);
    gather_w<<<4096, blk, 0, stream>>>(po, value_bf, out_loc, attn_bf);
    gemmln_w<true, false><<<512, blk, 0, stream>>>(
        attn_bf, pwT, pb, src, g1, b1, x1_bf, 256);
    gemm128_w<false, true, true><<<1024, blk, 0, stream>>>(
        x1_bf, w1T, bi1, hidden_bf, nullptr, nullptr, nullptr, 8, 1024, 256);
    gemmln_w<false, true><<<512, blk, 0, stream>>>(
        hidden_bf, w2T, bi2, x1_bf, g2, b2, out_x, 1024);
}

// Round 5
// 184.042 us; speedup vs baseline: 4.2931x; 4.2931x over previous
//
#include <hip/hip_runtime.h>
#include <math.h>

#define ROWS   8192
#define LQ     4096
#define NHEAD  8
#define NLVL   4
#define NPTS   4
#define HDIM   32

typedef __attribute__((ext_vector_type(8))) short v8s;
typedef __attribute__((ext_vector_type(4))) float v4f;
typedef __attribute__((ext_vector_type(8))) unsigned short v8u;

__device__ __forceinline__ unsigned short f2bf(float x) {
    unsigned int u = __float_as_uint(x);
    u += 0x7fffu + ((u >> 16) & 1u);
    return (unsigned short)(u >> 16);
}
__device__ __forceinline__ float bf2f(unsigned short x) {
    return __uint_as_float(((unsigned int)x) << 16);
}

// async global -> LDS, 16B per lane; LDS dest = wave-uniform base + lane*16
__device__ __forceinline__ void glds16(const void* g, void* l) {
    __builtin_amdgcn_global_load_lds(
        (const __attribute__((address_space(1))) unsigned int*)g,
        (__attribute__((address_space(3))) unsigned int*)l, 16, 0, 0);
}

// ---------------------------------------------------------------------------
// Prep: weight transposes + biascat.
// ---------------------------------------------------------------------------
__device__ __forceinline__ void trans_tile(const float* __restrict__ in,
                                           unsigned short* __restrict__ out,
                                           int K, int N, int ldout, int n_off,
                                           int bx, int by, int tid)
{
    __shared__ float t[32][33];
    int tx = tid & 31, ty = tid >> 5;           // 32 x 8
    int k0 = by << 5, n0 = bx << 5;
    #pragma unroll
    for (int i = 0; i < 4; i++)
        t[ty + i * 8][tx] = in[(size_t)(k0 + ty + i * 8) * N + n0 + tx];
    __syncthreads();
    #pragma unroll
    for (int i = 0; i < 4; i++)
        out[(size_t)(n_off + n0 + ty + i * 8) * ldout + k0 + tx] = f2bf(t[tx][ty + i * 8]);
}

__global__ __launch_bounds__(256) void prep_k(
    const float* __restrict__ vw, const float* __restrict__ ofw,
    const float* __restrict__ aww, const float* __restrict__ pw,
    const float* __restrict__ w1, const float* __restrict__ w2,
    unsigned short* __restrict__ Btcat, unsigned short* __restrict__ pwT,
    unsigned short* __restrict__ w1T, unsigned short* __restrict__ w2T,
    const float* __restrict__ vb, const float* __restrict__ ofb,
    const float* __restrict__ awb, float* __restrict__ biascat)
{
    int bid = blockIdx.x, tid = threadIdx.x;
    if (bid < 64) {                              // vw: 8x8
        int t = bid; trans_tile(vw, Btcat, 256, 256, 256, 0, t & 7, t >> 3, tid);
    } else if (bid < 128) {                      // ofw: 8x8
        int t = bid - 64; trans_tile(ofw, Btcat, 256, 256, 256, 256, t & 7, t >> 3, tid);
    } else if (bid < 160) {                      // aww: 4x8
        int t = bid - 128; trans_tile(aww, Btcat, 256, 128, 256, 512, t & 3, t >> 2, tid);
    } else if (bid < 224) {                      // pw: 8x8
        int t = bid - 160; trans_tile(pw, pwT, 256, 256, 256, 0, t & 7, t >> 3, tid);
    } else if (bid < 480) {                      // w1: 32x8
        int t = bid - 224; trans_tile(w1, w1T, 256, 1024, 256, 0, t & 31, t >> 5, tid);
    } else if (bid < 736) {                      // w2: 8x32
        int t = bid - 480; trans_tile(w2, w2T, 1024, 256, 1024, 0, t & 7, t >> 3, tid);
    } else {                                     // biascat
        biascat[tid] = vb[tid];
        biascat[tid + 256] = ofb[tid];
        if (tid < 128) biascat[tid + 512] = awb[tid];
    }
}

// ---------------------------------------------------------------------------
// bf16 MFMA GEMM, BM=64/BN=128/BK=32. XOR-swizzled glds16 LDS.
// AF32: A fp32 staged with in-register f2bf (1 chunk/thread).
// PROJ (N=640): [0,256) -> compact value bf16; [256,512) -> out_loc;
// [512,640) -> po logits.
// ---------------------------------------------------------------------------
template<bool PROJ, bool AF32, bool OUTBF, bool RELU, bool RES>
__global__ __launch_bounds__(256) void mfma_gemm128_k(
    const void* __restrict__ Araw,          // bf16 or fp32 [M][K]
    const unsigned short* __restrict__ Bt,  // bf16 [N][K]
    const float* __restrict__ bias,
    const float* __restrict__ res,
    void* __restrict__ Cout,
    unsigned short* __restrict__ vbf,       // PROJ only
    const float* __restrict__ refp,         // PROJ only
    float* __restrict__ oloc,               // PROJ only
    int M, int N, int K)
{
    __shared__ __align__(16) unsigned short As[2048];   // 256 chunks x 16B
    __shared__ __align__(16) unsigned short Bs[4096];   // 512 chunks x 16B
    const int tid = threadIdx.x;
    const int row0 = blockIdx.y << 6, col0 = blockIdx.x << 7;
    const int wid = tid >> 6, lane = tid & 63;
    const int wm = wid & 1, wn = wid >> 1;
    const int lr = lane & 15, kq = lane >> 4;

    v4f acc[2][4];
    #pragma unroll
    for (int i = 0; i < 2; i++)
        #pragma unroll
        for (int j = 0; j < 4; j++) acc[i][j] = (v4f){0.f, 0.f, 0.f, 0.f};

    for (int k0 = 0; k0 < K; k0 += 32) {
        float4 af0, af1;
        if constexpr (AF32) {
            const float* Af = (const float*)Araw;
            int r1 = tid >> 2, kk1 = ((tid & 3) + (r1 >> 2)) & 3;
            const float* p1 = Af + (size_t)(row0 + r1) * K + k0 + kk1 * 8;
            af0 = *(const float4*)p1; af1 = *(const float4*)(p1 + 4);
        }
        __syncthreads();
        if constexpr (AF32) {
            v8u u1;
            u1[0] = f2bf(af0.x); u1[1] = f2bf(af0.y); u1[2] = f2bf(af0.z); u1[3] = f2bf(af0.w);
            u1[4] = f2bf(af1.x); u1[5] = f2bf(af1.y); u1[6] = f2bf(af1.z); u1[7] = f2bf(af1.w);
            *(v8u*)(&As[tid * 8]) = u1;
        } else {
            const unsigned short* A = (const unsigned short*)Araw;
            int c = wid * 64 + lane;
            int row = c >> 2;
            int kk = ((c & 3) + (row >> 2)) & 3;
            glds16(A + (size_t)(row0 + row) * K + k0 + kk * 8,
                   &As[(wid * 64) * 8]);
        }
        #pragma unroll
        for (int i = 0; i < 2; i++) {
            int c = wid * 128 + i * 64 + lane;
            int row = c >> 2;
            int kk = ((c & 3) + (row >> 2)) & 3;
            glds16(Bt + (size_t)(col0 + row) * K + k0 + kk * 8,
                   &Bs[(wid * 128 + i * 64) * 8]);
        }
        __syncthreads();
        v8s bf[4];
        #pragma unroll
        for (int nt = 0; nt < 4; nt++) {
            int row = wn * 64 + nt * 16 + lr;
            int s = (kq - (row >> 2)) & 3;
            bf[nt] = *(const v8s*)(&Bs[(row * 4 + s) * 8]);
        }
        #pragma unroll
        for (int mt = 0; mt < 2; mt++) {
            int row = wm * 32 + mt * 16 + lr;
            int s = (kq - (row >> 2)) & 3;
            v8s af = *(const v8s*)(&As[(row * 4 + s) * 8]);
            #pragma unroll
            for (int nt = 0; nt < 4; nt++)
                acc[mt][nt] = __builtin_amdgcn_mfma_f32_16x16x32_bf16(af, bf[nt], acc[mt][nt], 0, 0, 0);
        }
    }

    const int rq = lane >> 4;
    #pragma unroll
    for (int mt = 0; mt < 2; mt++) {
        #pragma unroll
        for (int nt = 0; nt < 4; nt++) {
            int col = col0 + wn * 64 + nt * 16 + lr;
            float bv = bias[col];
            #pragma unroll
            for (int i = 0; i < 4; i++) {
                int row = row0 + wm * 32 + mt * 16 + rq * 4 + i;
                float v = acc[mt][nt][i] + bv;
                if (RELU) v = fmaxf(v, 0.f);
                if (RES)  v += res[(size_t)row * N + col];
                if (PROJ) {
                    if (col < 256) {
                        int b = row >> 12, rb = row & 4095;
                        int l = rb >> 10, pix = rb & 1023;
                        int h = col >> 5, d = col & 31;
                        size_t idx = ((size_t)(((b << 2) + l) * 8 + h) << 15) + (pix << 5) + d;
                        vbf[idx] = f2bf(v);
                    } else if (col < 512) {
                        int colm = col - 256;
                        int l = (colm >> 3) & 3, cc = colm & 1;
                        oloc[(size_t)row * 256 + colm] =
                            refp[(size_t)row * 8 + l * 2 + cc] + v * (1.f / 32.f);
                    } else {
                        ((float*)Cout)[(size_t)row * 128 + col - 512] = v;
                    }
                } else if (OUTBF) {
                    ((unsigned short*)Cout)[(size_t)row * N + col] = f2bf(v);
                } else {
                    ((float*)Cout)[(size_t)row * N + col] = v;
                }
            }
        }
    }
}

// ---------------------------------------------------------------------------
// FFN2: bf16 MFMA GEMM, BM=32/BN=128/BK=32 — N=256, K=1024.
// Grid (2,256) = 512 blocks (2/CU). A re-read x2 instead of x4 (vs BN=64):
// saves 32 MB of hidden traffic. Residual from bf16 x1_bf, fp32 out.
// ---------------------------------------------------------------------------
__global__ __launch_bounds__(256) void ffn2_k(
    const unsigned short* __restrict__ A,    // bf16 [M][1024] (hidden)
    const unsigned short* __restrict__ Bt,   // bf16 [256][1024] (w2T)
    const float* __restrict__ bias,          // [256]
    const unsigned short* __restrict__ resbf,// bf16 [M][256] (x1)
    float* __restrict__ Cout,                // fp32 [M][256]
    int M, int N, int K)
{
    __shared__ __align__(16) unsigned short As[1024];   // 128 chunks x 16B
    __shared__ __align__(16) unsigned short Bs[4096];   // 512 chunks x 16B
    const int tid = threadIdx.x;
    const int row0 = blockIdx.y << 5, col0 = blockIdx.x << 7;
    const int wid = tid >> 6, lane = tid & 63;
    const int lr = lane & 15, kq = lane >> 4;

    v4f acc[2][2];
    #pragma unroll
    for (int i = 0; i < 2; i++)
        #pragma unroll
        for (int j = 0; j < 2; j++) acc[i][j] = (v4f){0.f, 0.f, 0.f, 0.f};

    for (int k0 = 0; k0 < K; k0 += 32) {
        __syncthreads();
        if (wid < 2) {                         // A: 128 chunks on waves 0,1
            int c = wid * 64 + lane;
            int row = c >> 2;                  // 0..31
            int kk = ((c & 3) + (row >> 2)) & 3;
            glds16(A + (size_t)(row0 + row) * K + k0 + kk * 8,
                   &As[(wid * 64) * 8]);
        }
        #pragma unroll
        for (int i = 0; i < 2; i++) {          // B: 512 chunks, 2 per wave
            int c = wid * 128 + i * 64 + lane;
            int row = c >> 2;                  // 0..127
            int kk = ((c & 3) + (row >> 2)) & 3;
            glds16(Bt + (size_t)(col0 + row) * K + k0 + kk * 8,
                   &Bs[(wid * 128 + i * 64) * 8]);
        }
        __syncthreads();
        v8s bf[2];
        #pragma unroll
        for (int ct = 0; ct < 2; ct++) {
            int col = wid * 32 + ct * 16 + lr;
            int s = (kq - (col >> 2)) & 3;
            bf[ct] = *(const v8s*)(&Bs[(col * 4 + s) * 8]);
        }
        #pragma unroll
        for (int rt = 0; rt < 2; rt++) {
            int row = rt * 16 + lr;
            int s = (kq - (row >> 2)) & 3;
            v8s af = *(const v8s*)(&As[(row * 4 + s) * 8]);
            #pragma unroll
            for (int ct = 0; ct < 2; ct++)
                acc[rt][ct] = __builtin_amdgcn_mfma_f32_16x16x32_bf16(af, bf[ct], acc[rt][ct], 0, 0, 0);
        }
    }

    const int rq = lane >> 4;
    #pragma unroll
    for (int rt = 0; rt < 2; rt++) {
        #pragma unroll
        for (int ct = 0; ct < 2; ct++) {
            int col = col0 + wid * 32 + ct * 16 + lr;
            float bv = bias[col];
            #pragma unroll
            for (int i = 0; i < 4; i++) {
                int row = row0 + rt * 16 + rq * 4 + i;
                float v = acc[rt][ct][i] + bv + bf2f(resbf[(size_t)row * 256 + col]);
                Cout[(size_t)row * 256 + col] = v;
            }
        }
    }
}

// ---------------------------------------------------------------------------
// Full-row GEMM + residual + LayerNorm fused epilogue (outproj).
// Writes bf16 post-LN only (x1_bf).
// ---------------------------------------------------------------------------
__global__ __launch_bounds__(256) void mfma_gemm_ln_k(
    const unsigned short* __restrict__ A,   // bf16 [M][K]
    const unsigned short* __restrict__ Bt,  // bf16 [256][K]
    const float* __restrict__ bias,         // [256]
    const float* __restrict__ res,          // [M][256] fp32
    const float* __restrict__ g,
    const float* __restrict__ b,
    unsigned short* __restrict__ outbf,     // bf16 post-LN
    int M, int K)
{
    __shared__ __align__(16) unsigned short As[1024];   // 128 chunks x 16B
    __shared__ __align__(16) unsigned short Bs[8192];   // 1024 chunks x 16B
    __shared__ float red[2][32][4];
    const int tid = threadIdx.x;
    const int row0 = blockIdx.x << 5;
    const int wid = tid >> 6, lane = tid & 63;
    const int lr = lane & 15, kq = lane >> 4;
    const int rq = kq;

    v4f acc[2][4];
    #pragma unroll
    for (int i = 0; i < 2; i++)
        #pragma unroll
        for (int j = 0; j < 4; j++) acc[i][j] = (v4f){0.f, 0.f, 0.f, 0.f};

    for (int k0 = 0; k0 < K; k0 += 32) {
        __syncthreads();
        if (wid < 2) {                          // A: 128 chunks
            int c = wid * 64 + lane;
            int row = c >> 2;
            int kk = ((c & 3) + (row >> 2)) & 3;
            glds16(A + (size_t)(row0 + row) * K + k0 + kk * 8,
                   &As[(wid * 64) * 8]);
        }
        #pragma unroll
        for (int i = 0; i < 4; i++) {           // B: 1024 chunks
            int c = (wid * 4 + i) * 64 + lane;
            int col = c >> 2;
            int kk = ((c & 3) + (col >> 2)) & 3;
            glds16(Bt + (size_t)col * K + k0 + kk * 8,
                   &Bs[((wid * 4 + i) * 64) * 8]);
        }
        __syncthreads();
        v8s bf[4];
        #pragma unroll
        for (int ct = 0; ct < 4; ct++) {
            int col = wid * 64 + ct * 16 + lr;
            int s = (kq - (col >> 2)) & 3;
            bf[ct] = *(const v8s*)(&Bs[(col * 4 + s) * 8]);
        }
        #pragma unroll
        for (int rt = 0; rt < 2; rt++) {
            int rowl = rt * 16 + lr;
            int s = (kq - (rowl >> 2)) & 3;
            v8s af = *(const v8s*)(&As[(rowl * 4 + s) * 8]);
            #pragma unroll
            for (int ct = 0; ct < 4; ct++)
                acc[rt][ct] = __builtin_amdgcn_mfma_f32_16x16x32_bf16(af, bf[ct], acc[rt][ct], 0, 0, 0);
        }
    }

    float t[2][4][4];
    float s1[2][4], s2[2][4];
    #pragma unroll
    for (int rt = 0; rt < 2; rt++)
        #pragma unroll
        for (int i = 0; i < 4; i++) { s1[rt][i] = 0.f; s2[rt][i] = 0.f; }
    #pragma unroll
    for (int rt = 0; rt < 2; rt++) {
        #pragma unroll
        for (int ct = 0; ct < 4; ct++) {
            int col = wid * 64 + ct * 16 + lr;
            float bv = bias[col];
            #pragma unroll
            for (int i = 0; i < 4; i++) {
                int row = row0 + rt * 16 + rq * 4 + i;
                float v = acc[rt][ct][i] + bv + res[(size_t)row * 256 + col];
                t[rt][ct][i] = v;
                s1[rt][i] += v;
                s2[rt][i] += v * v;
            }
        }
    }
    #pragma unroll
    for (int o = 1; o < 16; o <<= 1) {
        #pragma unroll
        for (int rt = 0; rt < 2; rt++)
            #pragma unroll
            for (int i = 0; i < 4; i++) {
                s1[rt][i] += __shfl_xor(s1[rt][i], o);
                s2[rt][i] += __shfl_xor(s2[rt][i], o);
            }
    }
    if (lr == 0) {
        #pragma unroll
        for (int rt = 0; rt < 2; rt++)
            #pragma unroll
            for (int i = 0; i < 4; i++) {
                int rl = rt * 16 + rq * 4 + i;
                red[0][rl][wid] = s1[rt][i];
                red[1][rl][wid] = s2[rt][i];
            }
    }
    __syncthreads();
    float mu[2][4], rstd[2][4];
    #pragma unroll
    for (int rt = 0; rt < 2; rt++) {
        #pragma unroll
        for (int i = 0; i < 4; i++) {
            int rl = rt * 16 + rq * 4 + i;
            float S1 = red[0][rl][0] + red[0][rl][1] + red[0][rl][2] + red[0][rl][3];
            float S2 = red[1][rl][0] + red[1][rl][1] + red[1][rl][2] + red[1][rl][3];
            float m = S1 * (1.f / 256.f);
            mu[rt][i] = m;
            rstd[rt][i] = rsqrtf(S2 * (1.f / 256.f) - m * m + 1e-5f);
        }
    }
    #pragma unroll
    for (int rt = 0; rt < 2; rt++) {
        #pragma unroll
        for (int ct = 0; ct < 4; ct++) {
            int col = wid * 64 + ct * 16 + lr;
            float gg = g[col], bb = b[col];
            #pragma unroll
            for (int i = 0; i < 4; i++) {
                int row = row0 + rt * 16 + rq * 4 + i;
                float o = (t[rt][ct][i] - mu[rt][i]) * rstd[rt][i] * gg + bb;
                outbf[(size_t)row * 256 + col] = f2bf(o);
            }
        }
    }
}

// ---------------------------------------------------------------------------
// Fused gather, level-split, 16B taps. XCD-aware h.
// ---------------------------------------------------------------------------
__global__ __launch_bounds__(256) void fused_gather_k(
    const float* __restrict__ po,              // [ROWS][128] logits
    const unsigned short* __restrict__ vbf,    // [64][1024][32] bf16
    const float* __restrict__ loc,             // [ROWS][256] sampling locs
    unsigned short* __restrict__ attn_bf)      // [ROWS][256] bf16
{
    int tid = threadIdx.x;
    int g = tid >> 4, l = (tid >> 2) & 3, d8 = tid & 3;
    int h = blockIdx.x & 7;                    // XCD-aligned head
    int r = (blockIdx.x >> 3) * 16 + g;
    int b = r >> 12;

    float locv[8];
    *(float4*)(locv)     = *(const float4*)(loc + (size_t)r * 256 + h * 32 + l * 8);
    *(float4*)(locv + 4) = *(const float4*)(loc + (size_t)r * 256 + h * 32 + l * 8 + 4);

    float w4[4];
    *(float4*)(w4) = *(const float4*)(po + (size_t)r * 128 + h * 16 + l * 4);
    float m = fmaxf(fmaxf(w4[0], w4[1]), fmaxf(w4[2], w4[3]));
    m = fmaxf(m, __shfl_xor(m, 4));
    m = fmaxf(m, __shfl_xor(m, 8));
    float s = 0.f;
    #pragma unroll
    for (int p = 0; p < 4; p++) { w4[p] = __expf(w4[p] - m); s += w4[p]; }
    s += __shfl_xor(s, 4);
    s += __shfl_xor(s, 8);
    float inv = 1.f / s;

    const unsigned short* vbase =
        vbf + (((size_t)(((b << 2) + l) * 8 + h)) << 15) + d8 * 8;

    float acc[8];
    #pragma unroll
    for (int k = 0; k < 8; k++) acc[k] = 0.f;

    #pragma unroll
    for (int pp = 0; pp < 2; pp++) {           // 2 points per batch, 8 taps staged
        v8u uv[8];
        float cw[8];
        #pragma unroll
        for (int p2 = 0; p2 < 2; p2++) {
            int p = pp * 2 + p2;
            float xf = locv[p * 2] * 32.f - 0.5f, yf = locv[p * 2 + 1] * 32.f - 0.5f;
            float x0f = floorf(xf), y0f = floorf(yf);
            float fx = xf - x0f, fy = yf - y0f;
            int x0 = (int)x0f, y0 = (int)y0f;
            float wgt = w4[p] * inv;
            #pragma unroll
            for (int dy = 0; dy < 2; dy++) {
                #pragma unroll
                for (int dx = 0; dx < 2; dx++) {
                    int idx = p2 * 4 + dy * 2 + dx;
                    int xi = x0 + dx, yi = y0 + dy;
                    float wt = (dx ? fx : 1.f - fx) * (dy ? fy : 1.f - fy);
                    bool valid = (xi >= 0) & (xi < 32) & (yi >= 0) & (yi < 32);
                    int xc = min(max(xi, 0), 31), yc = min(max(yi, 0), 31);
                    cw[idx] = valid ? (wgt * wt) : 0.f;
                    uv[idx] = *(const v8u*)(vbase + (size_t)((yc << 5) + xc) * 32);
                }
            }
        }
        #pragma unroll
        for (int idx = 0; idx < 8; idx++) {
            float c = cw[idx];
            #pragma unroll
            for (int k = 0; k < 8; k++)
                acc[k] += c * bf2f(uv[idx][k]);
        }
    }
    #pragma unroll
    for (int k = 0; k < 8; k++) {
        acc[k] += __shfl_xor(acc[k], 4);
        acc[k] += __shfl_xor(acc[k], 8);
    }
    if (l == 0) {
        v8u o;
        #pragma unroll
        for (int k = 0; k < 8; k++) o[k] = f2bf(acc[k]);
        *(v8u*)(attn_bf + (size_t)r * 256 + h * 32 + d8 * 8) = o;
    }
}

// ---------------------------------------------------------------------------
// In-place LayerNorm over 256 cols.
// ---------------------------------------------------------------------------
__global__ __launch_bounds__(256) void layernorm_k(
    float* __restrict__ x, const float* __restrict__ g, const float* __restrict__ b)
{
    int lane = threadIdx.x & 63;
    int wv = threadIdx.x >> 6;
    int row = blockIdx.x * 4 + wv;
    int c = lane << 2;
    float4 v = *(const float4*)(x + (size_t)row * 256 + c);
    float s = v.x + v.y + v.z + v.w;
    #pragma unroll
    for (int o = 1; o < 64; o <<= 1) s += __shfl_xor(s, o);
    float mu = s * (1.f / 256.f);
    float d0 = v.x - mu, d1 = v.y - mu, d2 = v.z - mu, d3 = v.w - mu;
    float vs = d0 * d0 + d1 * d1 + d2 * d2 + d3 * d3;
    #pragma unroll
    for (int o = 1; o < 64; o <<= 1) vs += __shfl_xor(vs, o);
    float rstd = rsqrtf(vs * (1.f / 256.f) + 1e-5f);
    float4 gg = *(const float4*)(g + c);
    float4 bb = *(const float4*)(b + c);
    float4 o4;
    o4.x = d0 * rstd * gg.x + bb.x;
    o4.y = d1 * rstd * gg.y + bb.y;
    o4.z = d2 * rstd * gg.z + bb.z;
    o4.w = d3 * rstd * gg.w + bb.w;
    *(float4*)(x + (size_t)row * 256 + c) = o4;
}

// ---------------------------------------------------------------------------
extern "C" void kernel_launch(void* const* d_in, const int* in_sizes, int n_in,
                              void* d_out, int out_size, void* d_ws, size_t ws_size,
                              hipStream_t stream)
{
    const float* src   = (const float*)d_in[0];
    const float* refp  = (const float*)d_in[2];
    const float* vw    = (const float*)d_in[3];
    const float* vb    = (const float*)d_in[4];
    const float* ofw   = (const float*)d_in[5];
    const float* ofb   = (const float*)d_in[6];
    const float* aww   = (const float*)d_in[7];
    const float* awb   = (const float*)d_in[8];
    const float* pw    = (const float*)d_in[9];
    const float* pb    = (const float*)d_in[10];
    const float* g1    = (const float*)d_in[11];
    const float* b1    = (const float*)d_in[12];
    const float* w1    = (const float*)d_in[13];
    const float* bi1   = (const float*)d_in[14];
    const float* w2    = (const float*)d_in[15];
    const float* bi2   = (const float*)d_in[16];
    const float* g2    = (const float*)d_in[17];
    const float* b2    = (const float*)d_in[18];

    float* ws = (float*)d_ws;
    float*          po        = ws;                               // 1,048,576 f
    unsigned short* value_bf  = (unsigned short*)(ws + 1048576);  // 2,097,152 us
    unsigned short* x1_bf     = (unsigned short*)(ws + 2097152);
    unsigned short* attn_bf   = (unsigned short*)(ws + 3145728);
    unsigned short* hidden_bf = (unsigned short*)(ws + 4194304);  // 8,388,608 us
    unsigned short* Btcat     = (unsigned short*)(ws + 8388608);  // 163,840 us
    unsigned short* pwT       = (unsigned short*)(ws + 8470528);
    unsigned short* w1T       = (unsigned short*)(ws + 8503296);
    unsigned short* w2T       = (unsigned short*)(ws + 8634368);
    float*          biascat   = ws + 8765440;                     // 640 f
    unsigned short* src_bf    = (unsigned short*)(ws + 8766080);  // unused

    float* out_x   = (float*)d_out;
    float* out_loc = out_x + 2097152;
    (void)src_bf;

    dim3 blk(256);

    // --- weight prep (bf16, transposed) + biascat ---
    prep_k<<<737, blk, 0, stream>>>(vw, ofw, aww, pw, w1, w2,
                                    Btcat, pwT, w1T, w2T, vb, ofb, awb, biascat);

    // --- fused projections (A converted in-kernel from fp32 src), BN=128
    mfma_gemm128_k<true, true, false, false, false><<<dim3(5, 128), blk, 0, stream>>>(
        src, Btcat, biascat, nullptr, po, value_bf, refp, out_loc, ROWS, 640, 256);

    // --- softmax + deformable gather -> attn_bf
    fused_gather_k<<<4096, blk, 0, stream>>>(po, value_bf, out_loc, attn_bf);

    // --- output projection + residual(src) + LN1 fused -> x1_bf only
    mfma_gemm_ln_k<<<256, blk, 0, stream>>>(
        attn_bf, pwT, pb, src, g1, b1, x1_bf, ROWS, 256);

    // --- FFN1: relu(x1 @ w1 + b1) -> hidden_bf, BN=128
    mfma_gemm128_k<false, false, true, true, false><<<dim3(8, 128), blk, 0, stream>>>(
        x1_bf, w1T, bi1, nullptr, hidden_bf, nullptr, nullptr, nullptr, ROWS, 1024, 256);

    // --- FFN2 + residual(x1_bf) -> out_x (BM=32/BN=128, A re-read x2), then LN2
    ffn2_k<<<dim3(2, 256), blk, 0, stream>>>(
        hidden_bf, w2T, bi2, x1_bf, out_x, ROWS, 256, 1024);
    layernorm_k<<<2048, blk, 0, stream>>>(out_x, g2, b2);
}